// Round 1
// baseline (241.170 us; speedup 1.0000x reference)
//
#include <hip/hip_runtime.h>
#include <hip/hip_bf16.h>
#include <math.h>

// NT-Xent loss, N=4096, D=256 -> 2N=8192 rows.
// K1: normalize rows of concat(z1,z2), store bf16 zhat + fp32 invnorm (ws).
// K2: fused Gram-matrix: rowsum[r] = sum_c exp(10 * zhat_r . zhat_c), diag excluded.
//     bf16 MFMA 16x16x32, 128x128 block tile, 4 waves x (4x4) acc grid.
// K3: sim_pos from exact fp32 dot(z1_i, z2_i) * invnorms * 10; loss = mean(log(rowsum)-sp).

static constexpr int ROWS  = 8192;   // 2N
static constexpr int NPAIR = 4096;   // N
static constexpr int DIM   = 256;    // D
static constexpr float TEMP_INV = 10.0f;

typedef short bf16x8 __attribute__((ext_vector_type(8)));
typedef float f32x4  __attribute__((ext_vector_type(4)));

// ---------------- K1: row normalize ----------------
__global__ void normalize_kernel(const float* __restrict__ z1,
                                 const float* __restrict__ z2,
                                 __hip_bfloat16* __restrict__ zhat,
                                 float* __restrict__ invnorm) {
    int row = blockIdx.x;           // 0..8191
    int tid = threadIdx.x;          // 0..255 == column
    const float* src = (row < NPAIR) ? (z1 + (size_t)row * DIM)
                                     : (z2 + (size_t)(row - NPAIR) * DIM);
    float v = src[tid];
    float ss = v * v;
    #pragma unroll
    for (int m = 1; m < 64; m <<= 1) ss += __shfl_xor(ss, m);
    __shared__ float wpart[4];
    if ((tid & 63) == 0) wpart[tid >> 6] = ss;
    __syncthreads();
    float tot = wpart[0] + wpart[1] + wpart[2] + wpart[3];
    float invn = 1.0f / fmaxf(sqrtf(tot), 1e-12f);
    zhat[(size_t)row * DIM + tid] = __float2bfloat16(v * invn);
    if (tid == 0) invnorm[row] = invn;
}

// ---------------- K2: fused Gram + exp + rowsum ----------------
static constexpr int BK = 64;
static constexpr int LDS_STRIDE = 72;   // 64 + 8 shorts pad: keeps 16B align, 2-way max on frag reads

__global__ void __launch_bounds__(256) simsum_kernel(
        const __hip_bfloat16* __restrict__ zhat,
        float* __restrict__ rowsum) {
    __shared__ __align__(16) short As[128 * LDS_STRIDE];
    __shared__ __align__(16) short Bs[128 * LDS_STRIDE];

    const int tid  = threadIdx.x;
    const int lane = tid & 63;
    const int wave = tid >> 6;
    const int rowBase = blockIdx.y * 128;
    const int colBase = blockIdx.x * 128;
    const int waveRow = (wave >> 1) * 64;
    const int waveCol = (wave & 1) * 64;
    const int lc   = lane & 15;
    const int quad = lane >> 4;

    f32x4 acc[4][4];
    #pragma unroll
    for (int i = 0; i < 4; i++)
        #pragma unroll
        for (int j = 0; j < 4; j++)
            acc[i][j] = (f32x4)(0.0f);

    const short* zs = (const short*)zhat;
    const int ldRow   = tid >> 3;        // 0..31 (rows per pass)
    const int ldChunk = (tid & 7) * 8;   // short offset within 64-wide K slab

    for (int kt = 0; kt < DIM; kt += BK) {
        #pragma unroll
        for (int p = 0; p < 4; p++) {
            int r = ldRow + p * 32;
            const short* ga = zs + (size_t)(rowBase + r) * DIM + kt + ldChunk;
            *(int4*)(&As[r * LDS_STRIDE + ldChunk]) = *(const int4*)ga;
            const short* gb = zs + (size_t)(colBase + r) * DIM + kt + ldChunk;
            *(int4*)(&Bs[r * LDS_STRIDE + ldChunk]) = *(const int4*)gb;
        }
        __syncthreads();
        #pragma unroll
        for (int ks = 0; ks < BK; ks += 32) {
            bf16x8 af[4], bfr[4];
            int ko = ks + quad * 8;
            #pragma unroll
            for (int i = 0; i < 4; i++)
                af[i] = *(const bf16x8*)(&As[(waveRow + 16 * i + lc) * LDS_STRIDE + ko]);
            #pragma unroll
            for (int j = 0; j < 4; j++)
                bfr[j] = *(const bf16x8*)(&Bs[(waveCol + 16 * j + lc) * LDS_STRIDE + ko]);
            #pragma unroll
            for (int i = 0; i < 4; i++)
                #pragma unroll
                for (int j = 0; j < 4; j++)
                    acc[i][j] = __builtin_amdgcn_mfma_f32_16x16x32_bf16(
                        af[i], bfr[j], acc[i][j], 0, 0, 0);
        }
        __syncthreads();
    }

    // Epilogue: C/D layout (16x16): col = lane&15, row = quad*4 + reg  [m89-verified]
    #pragma unroll
    for (int i = 0; i < 4; i++) {
        #pragma unroll
        for (int r = 0; r < 4; r++) {
            int grow = rowBase + waveRow + 16 * i + quad * 4 + r;
            float s = 0.0f;
            #pragma unroll
            for (int j = 0; j < 4; j++) {
                int gcol = colBase + waveCol + 16 * j + lc;
                float v = acc[i][j][r] * TEMP_INV;
                s += (grow == gcol) ? 0.0f : __expf(v);
            }
            // reduce the 16 lanes of this quad (they hold the 16 columns of row grow)
            s += __shfl_xor(s, 1);
            s += __shfl_xor(s, 2);
            s += __shfl_xor(s, 4);
            s += __shfl_xor(s, 8);
            if (lc == 0) atomicAdd(&rowsum[grow], s);
        }
    }
}

// ---------------- K3: positive pairs + final loss ----------------
__global__ void loss_kernel(const float* __restrict__ z1,
                            const float* __restrict__ z2,
                            const float* __restrict__ invnorm,
                            const float* __restrict__ rowsum,
                            float* __restrict__ out) {
    int i = blockIdx.x;     // 0..4095
    int tid = threadIdx.x;  // 0..255
    float d = z1[(size_t)i * DIM + tid] * z2[(size_t)i * DIM + tid];
    #pragma unroll
    for (int m = 1; m < 64; m <<= 1) d += __shfl_xor(d, m);
    __shared__ float wpart[4];
    if ((tid & 63) == 0) wpart[tid >> 6] = d;
    __syncthreads();
    if (tid == 0) {
        float dot = wpart[0] + wpart[1] + wpart[2] + wpart[3];
        float sp = dot * invnorm[i] * invnorm[i + NPAIR] * TEMP_INV;
        float c = (logf(rowsum[i]) - sp) + (logf(rowsum[i + NPAIR]) - sp);
        atomicAdd(out, c * (1.0f / ROWS));
    }
}

extern "C" void kernel_launch(void* const* d_in, const int* in_sizes, int n_in,
                              void* d_out, int out_size, void* d_ws, size_t ws_size,
                              hipStream_t stream) {
    const float* z1 = (const float*)d_in[0];
    const float* z2 = (const float*)d_in[1];
    float* out = (float*)d_out;

    char* ws = (char*)d_ws;
    __hip_bfloat16* zhat = (__hip_bfloat16*)ws;                       // 8192*256*2 = 4 MiB
    float* invnorm = (float*)(ws + (size_t)ROWS * DIM * 2);           // 32 KiB
    float* rowsum  = (float*)(ws + (size_t)ROWS * DIM * 2 + ROWS * 4);// 32 KiB

    hipMemsetAsync(out, 0, sizeof(float), stream);
    hipMemsetAsync(rowsum, 0, ROWS * sizeof(float), stream);

    normalize_kernel<<<ROWS, 256, 0, stream>>>(z1, z2, zhat, invnorm);
    simsum_kernel<<<dim3(ROWS / 128, ROWS / 128), 256, 0, stream>>>(zhat, rowsum);
    loss_kernel<<<NPAIR, 256, 0, stream>>>(z1, z2, invnorm, rowsum, out);
}

// Round 2
// 169.949 us; speedup vs baseline: 1.4191x; 1.4191x over previous
//
#include <hip/hip_runtime.h>
#include <hip/hip_bf16.h>
#include <math.h>

// NT-Xent loss, N=4096, D=256 -> 2N=8192 rows.
// K1 (prep): normalize rows of concat(z1,z2) -> bf16 zhat + fp32 invnorm; zero rowsum/out.
// K2 (simsum): symmetric fused Gram: for upper-tri 128x128 tiles only,
//     rowsum[r] += sum_c exp(10*zhat_r.zhat_c); off-diag tiles also add the
//     transposed (column) sums. bf16 MFMA 16x16x32, global_load_lds staging,
//     XOR-swizzled LDS (swizzle applied on the GLOBAL address side since
//     global_load_lds dest is wave-uniform base + lane*16 -- no padding allowed).
// K3 (loss): sim_pos from exact fp32 dot(z1_i,z2_i); loss = mean(log(rowsum)-sp).

static constexpr int ROWS  = 8192;   // 2N
static constexpr int NPAIR = 4096;   // N
static constexpr int DIM   = 256;    // D
static constexpr float EXP_SCALE = 14.426950408889634f;  // 10 / ln(2), for exp2

typedef short bf16x8 __attribute__((ext_vector_type(8)));
typedef float f32x4  __attribute__((ext_vector_type(4)));

__device__ __forceinline__ void glds16(const void* g, void* l) {
    __builtin_amdgcn_global_load_lds(
        (const __attribute__((address_space(1))) void*)g,
        (__attribute__((address_space(3))) void*)l, 16, 0, 0);
}

__device__ __forceinline__ unsigned short f2bf(float x) {
    __hip_bfloat16 b = __float2bfloat16(x);
    unsigned short u;
    __builtin_memcpy(&u, &b, 2);
    return u;
}

// ---------------- K1: normalize + zero scratch ----------------
__global__ void __launch_bounds__(256) prep_kernel(
        const float* __restrict__ z1, const float* __restrict__ z2,
        unsigned short* __restrict__ zhat, float* __restrict__ invnorm,
        float* __restrict__ rowsum, float* __restrict__ out) {
    const int tid  = threadIdx.x;
    const int wave = tid >> 6;
    const int lane = tid & 63;
    const int row  = blockIdx.x * 4 + wave;           // 0..8191, one wave per row
    const float* src = (row < NPAIR) ? (z1 + (size_t)row * DIM)
                                     : (z2 + (size_t)(row - NPAIR) * DIM);
    float4 v = ((const float4*)src)[lane];
    float ss = v.x * v.x + v.y * v.y + v.z * v.z + v.w * v.w;
    #pragma unroll
    for (int m = 1; m < 64; m <<= 1) ss += __shfl_xor(ss, m);
    float invn = 1.0f / fmaxf(sqrtf(ss), 1e-12f);
    ushort4 o;
    o.x = f2bf(v.x * invn); o.y = f2bf(v.y * invn);
    o.z = f2bf(v.z * invn); o.w = f2bf(v.w * invn);
    ((ushort4*)(zhat + (size_t)row * DIM))[lane] = o;
    if (lane == 0) invnorm[row] = invn;
    if (tid < 4) rowsum[blockIdx.x * 4 + tid] = 0.0f;   // 2048 blocks x 4 = 8192
    if (blockIdx.x == 0 && tid == 0) out[0] = 0.0f;
}

// ---------------- K2: symmetric fused Gram + exp + rowsum ----------------
// grid: 64*65/2 = 2080 blocks (upper-triangular tile pairs), 256 threads.
__global__ void __launch_bounds__(256) simsum_kernel(
        const unsigned short* __restrict__ zs, float* __restrict__ rowsum) {
    __shared__ __align__(16) unsigned short As[128 * 64];
    __shared__ __align__(16) unsigned short Bs[128 * 64];

    // decode linear tile index -> (by, bx), bx >= by
    const int t = blockIdx.x;
    int by = (int)floorf((129.0f - sqrtf(16641.0f - 8.0f * (float)t)) * 0.5f);
    by = max(0, min(by, 63));
    while (64 * (by + 1) - ((by + 1) * by) / 2 <= t) by++;
    while (64 * by - (by * (by - 1)) / 2 > t) by--;
    const int bx = by + (t - (64 * by - (by * (by - 1)) / 2));
    const int rowBase = by * 128;
    const int colBase = bx * 128;
    const bool diag = (bx == by);

    const int tid  = threadIdx.x;
    const int wave = tid >> 6;
    const int lane = tid & 63;
    const int lc   = lane & 15;
    const int quad = lane >> 4;
    const int waveRow = (wave >> 1) * 64;
    const int waveCol = (wave & 1) * 64;

    // staging decomposition: lane -> (row-in-8-group, chunk slot); XOR swizzle
    // physical slot s at row R holds logical k-chunk s ^ (R & 7).
    const int r_in = lane >> 3;       // 0..7
    const int slot = lane & 7;        // 0..7 (16B chunks of 8 shorts)
    const int kc   = slot ^ r_in;     // logical chunk this lane must fetch

    f32x4 acc[4][4];
    #pragma unroll
    for (int i = 0; i < 4; i++)
        #pragma unroll
        for (int j = 0; j < 4; j++)
            acc[i][j] = (f32x4)(0.0f);

    for (int kt = 0; kt < DIM; kt += 64) {
        #pragma unroll
        for (int g = 0; g < 4; g++) {
            const int rl = wave * 32 + g * 8;  // base row of this 8-row group
            glds16(zs + (size_t)(rowBase + rl + r_in) * DIM + kt + kc * 8,
                   &As[rl * 64]);
            glds16(zs + (size_t)(colBase + rl + r_in) * DIM + kt + kc * 8,
                   &Bs[rl * 64]);
        }
        __syncthreads();
        #pragma unroll
        for (int ks = 0; ks < 64; ks += 32) {
            const int kchunk = (ks >> 3) + quad;   // logical chunk for this quad
            bf16x8 af[4], bfr[4];
            #pragma unroll
            for (int i = 0; i < 4; i++) {
                const int R = waveRow + 16 * i + lc;
                af[i] = *(const bf16x8*)&As[R * 64 + (kchunk ^ (R & 7)) * 8];
            }
            #pragma unroll
            for (int j = 0; j < 4; j++) {
                const int R = waveCol + 16 * j + lc;
                bfr[j] = *(const bf16x8*)&Bs[R * 64 + (kchunk ^ (R & 7)) * 8];
            }
            #pragma unroll
            for (int i = 0; i < 4; i++)
                #pragma unroll
                for (int j = 0; j < 4; j++)
                    acc[i][j] = __builtin_amdgcn_mfma_f32_16x16x32_bf16(
                        af[i], bfr[j], acc[i][j], 0, 0, 0);
        }
        __syncthreads();
    }

    // Epilogue. C/D 16x16 layout: col = lane&15, row = quad*4 + reg [m89].
    if (diag) {
        #pragma unroll
        for (int i = 0; i < 4; i++) {
            #pragma unroll
            for (int r = 0; r < 4; r++) {
                const int grow = rowBase + waveRow + 16 * i + quad * 4 + r;
                float s = 0.0f;
                #pragma unroll
                for (int j = 0; j < 4; j++) {
                    const int gcol = colBase + waveCol + 16 * j + lc;
                    float e = __builtin_amdgcn_exp2f(acc[i][j][r] * EXP_SCALE);
                    s += (grow == gcol) ? 0.0f : e;
                }
                s += __shfl_xor(s, 1); s += __shfl_xor(s, 2);
                s += __shfl_xor(s, 4); s += __shfl_xor(s, 8);
                if (lc == 0) atomicAdd(&rowsum[grow], s);
            }
        }
    } else {
        float colacc[4] = {0.0f, 0.0f, 0.0f, 0.0f};
        #pragma unroll
        for (int i = 0; i < 4; i++) {
            #pragma unroll
            for (int r = 0; r < 4; r++) {
                const int grow = rowBase + waveRow + 16 * i + quad * 4 + r;
                float s = 0.0f;
                #pragma unroll
                for (int j = 0; j < 4; j++) {
                    float e = __builtin_amdgcn_exp2f(acc[i][j][r] * EXP_SCALE);
                    s += e;
                    colacc[j] += e;
                }
                s += __shfl_xor(s, 1); s += __shfl_xor(s, 2);
                s += __shfl_xor(s, 4); s += __shfl_xor(s, 8);
                if (lc == 0) atomicAdd(&rowsum[grow], s);
            }
        }
        #pragma unroll
        for (int j = 0; j < 4; j++) {
            float c = colacc[j];
            c += __shfl_xor(c, 16); c += __shfl_xor(c, 32);
            if (lane < 16) atomicAdd(&rowsum[colBase + waveCol + 16 * j + lc], c);
        }
    }
}

// ---------------- K3: positive pairs + final loss ----------------
__global__ void __launch_bounds__(256) loss_kernel(
        const float* __restrict__ z1, const float* __restrict__ z2,
        const float* __restrict__ invnorm, const float* __restrict__ rowsum,
        float* __restrict__ out) {
    const int tid  = threadIdx.x;
    const int wave = tid >> 6;
    const int lane = tid & 63;
    const int p = blockIdx.x * 4 + wave;     // 0..4095, one wave per pair
    float4 a = ((const float4*)(z1 + (size_t)p * DIM))[lane];
    float4 b = ((const float4*)(z2 + (size_t)p * DIM))[lane];
    float d = a.x * b.x + a.y * b.y + a.z * b.z + a.w * b.w;
    #pragma unroll
    for (int m = 1; m < 64; m <<= 1) d += __shfl_xor(d, m);
    if (lane == 0) {
        float sp = d * invnorm[p] * invnorm[p + NPAIR] * 10.0f;
        float c = logf(rowsum[p]) + logf(rowsum[p + NPAIR]) - 2.0f * sp;
        atomicAdd(out, c * (1.0f / ROWS));
    }
}

extern "C" void kernel_launch(void* const* d_in, const int* in_sizes, int n_in,
                              void* d_out, int out_size, void* d_ws, size_t ws_size,
                              hipStream_t stream) {
    const float* z1 = (const float*)d_in[0];
    const float* z2 = (const float*)d_in[1];
    float* out = (float*)d_out;

    char* ws = (char*)d_ws;
    unsigned short* zhat = (unsigned short*)ws;                        // 4 MiB
    float* invnorm = (float*)(ws + (size_t)ROWS * DIM * 2);            // 32 KiB
    float* rowsum  = (float*)(ws + (size_t)ROWS * DIM * 2 + ROWS * 4); // 32 KiB

    prep_kernel<<<ROWS / 4, 256, 0, stream>>>(z1, z2, zhat, invnorm, rowsum, out);
    simsum_kernel<<<64 * 65 / 2, 256, 0, stream>>>(zhat, rowsum);
    loss_kernel<<<NPAIR / 4, 256, 0, stream>>>(z1, z2, invnorm, rowsum, out);
}

// Round 3
// 122.768 us; speedup vs baseline: 1.9644x; 1.3843x over previous
//
#include <hip/hip_runtime.h>
#include <hip/hip_bf16.h>
#include <math.h>

// NT-Xent loss, N=4096, D=256 -> 2N=8192 rows.
// K1 (prep): normalize rows of concat(z1,z2) -> bf16 zhat + fp32 invnorm; zero rowsum.
// K2 (simsum): symmetric fused Gram over upper-tri 128x128 tiles; off-diag tiles
//     contribute both row-sums and (transposed) column-sums. bf16 MFMA 16x16x32,
//     global_load_lds width-16 staging, XOR-swizzled LDS (swizzle on the GLOBAL
//     address side: glds dest is wave-uniform base + lane*16, no padding allowed).
// K3 (loss): per-pair contribution, block-level LDS reduce -> partials[block]
//     (NO contended single-address atomics -- R2 showed 4096 atomicAdds to one
//      address cost 54 us).
// K4 (final): one block sums 1024 partials -> out.

static constexpr int ROWS  = 8192;   // 2N
static constexpr int NPAIR = 4096;   // N
static constexpr int DIM   = 256;    // D
static constexpr float EXP_SCALE = 14.426950408889634f;  // 10 / ln(2), for exp2
static constexpr int LOSS_BLOCKS = NPAIR / 4;            // 1024

typedef short bf16x8 __attribute__((ext_vector_type(8)));
typedef float f32x4  __attribute__((ext_vector_type(4)));

__device__ __forceinline__ void glds16(const void* g, void* l) {
    __builtin_amdgcn_global_load_lds(
        (const __attribute__((address_space(1))) void*)g,
        (__attribute__((address_space(3))) void*)l, 16, 0, 0);
}

__device__ __forceinline__ unsigned short f2bf(float x) {
    __hip_bfloat16 b = __float2bfloat16(x);
    unsigned short u;
    __builtin_memcpy(&u, &b, 2);
    return u;
}

// ---------------- K1: normalize + zero rowsum ----------------
__global__ void __launch_bounds__(256) prep_kernel(
        const float* __restrict__ z1, const float* __restrict__ z2,
        unsigned short* __restrict__ zhat, float* __restrict__ invnorm,
        float* __restrict__ rowsum) {
    const int tid  = threadIdx.x;
    const int wave = tid >> 6;
    const int lane = tid & 63;
    const int row  = blockIdx.x * 4 + wave;           // 0..8191, one wave per row
    const float* src = (row < NPAIR) ? (z1 + (size_t)row * DIM)
                                     : (z2 + (size_t)(row - NPAIR) * DIM);
    float4 v = ((const float4*)src)[lane];
    float ss = v.x * v.x + v.y * v.y + v.z * v.z + v.w * v.w;
    #pragma unroll
    for (int m = 1; m < 64; m <<= 1) ss += __shfl_xor(ss, m);
    float invn = 1.0f / fmaxf(sqrtf(ss), 1e-12f);
    ushort4 o;
    o.x = f2bf(v.x * invn); o.y = f2bf(v.y * invn);
    o.z = f2bf(v.z * invn); o.w = f2bf(v.w * invn);
    ((ushort4*)(zhat + (size_t)row * DIM))[lane] = o;
    if (lane == 0) invnorm[row] = invn;
    if (tid < 4) rowsum[blockIdx.x * 4 + tid] = 0.0f;   // 2048 blocks x 4 = 8192
}

// ---------------- K2: symmetric fused Gram + exp + rowsum ----------------
// grid: 64*65/2 = 2080 blocks (upper-triangular tile pairs), 256 threads.
__global__ void __launch_bounds__(256) simsum_kernel(
        const unsigned short* __restrict__ zs, float* __restrict__ rowsum) {
    __shared__ __align__(16) unsigned short As[128 * 64];
    __shared__ __align__(16) unsigned short Bs[128 * 64];

    // decode linear tile index -> (by, bx), bx >= by
    const int t = blockIdx.x;
    int by = (int)floorf((129.0f - sqrtf(16641.0f - 8.0f * (float)t)) * 0.5f);
    by = max(0, min(by, 63));
    while (64 * (by + 1) - ((by + 1) * by) / 2 <= t) by++;
    while (64 * by - (by * (by - 1)) / 2 > t) by--;
    const int bx = by + (t - (64 * by - (by * (by - 1)) / 2));
    const int rowBase = by * 128;
    const int colBase = bx * 128;
    const bool diag = (bx == by);

    const int tid  = threadIdx.x;
    const int wave = tid >> 6;
    const int lane = tid & 63;
    const int lc   = lane & 15;
    const int quad = lane >> 4;
    const int waveRow = (wave >> 1) * 64;
    const int waveCol = (wave & 1) * 64;

    // staging decomposition: lane -> (row-in-8-group, chunk slot); XOR swizzle:
    // physical slot s at row R holds logical k-chunk s ^ (R & 7).
    const int r_in = lane >> 3;       // 0..7
    const int slot = lane & 7;        // 0..7 (16B chunks of 8 shorts)
    const int kc   = slot ^ r_in;     // logical chunk this lane must fetch

    f32x4 acc[4][4];
    #pragma unroll
    for (int i = 0; i < 4; i++)
        #pragma unroll
        for (int j = 0; j < 4; j++)
            acc[i][j] = (f32x4)(0.0f);

    for (int kt = 0; kt < DIM; kt += 64) {
        #pragma unroll
        for (int g = 0; g < 4; g++) {
            const int rl = wave * 32 + g * 8;  // base row of this 8-row group
            glds16(zs + (size_t)(rowBase + rl + r_in) * DIM + kt + kc * 8,
                   &As[rl * 64]);
            glds16(zs + (size_t)(colBase + rl + r_in) * DIM + kt + kc * 8,
                   &Bs[rl * 64]);
        }
        __syncthreads();
        #pragma unroll
        for (int ks = 0; ks < 64; ks += 32) {
            const int kchunk = (ks >> 3) + quad;   // logical chunk for this quad
            bf16x8 af[4], bfr[4];
            #pragma unroll
            for (int i = 0; i < 4; i++) {
                const int R = waveRow + 16 * i + lc;
                af[i] = *(const bf16x8*)&As[R * 64 + (kchunk ^ (R & 7)) * 8];
            }
            #pragma unroll
            for (int j = 0; j < 4; j++) {
                const int R = waveCol + 16 * j + lc;
                bfr[j] = *(const bf16x8*)&Bs[R * 64 + (kchunk ^ (R & 7)) * 8];
            }
            #pragma unroll
            for (int i = 0; i < 4; i++)
                #pragma unroll
                for (int j = 0; j < 4; j++)
                    acc[i][j] = __builtin_amdgcn_mfma_f32_16x16x32_bf16(
                        af[i], bfr[j], acc[i][j], 0, 0, 0);
        }
        __syncthreads();
    }

    // Epilogue. C/D 16x16 layout: col = lane&15, row = quad*4 + reg [m89].
    if (diag) {
        #pragma unroll
        for (int i = 0; i < 4; i++) {
            #pragma unroll
            for (int r = 0; r < 4; r++) {
                const int grow = rowBase + waveRow + 16 * i + quad * 4 + r;
                float s = 0.0f;
                #pragma unroll
                for (int j = 0; j < 4; j++) {
                    const int gcol = colBase + waveCol + 16 * j + lc;
                    float e = __builtin_amdgcn_exp2f(acc[i][j][r] * EXP_SCALE);
                    s += (grow == gcol) ? 0.0f : e;
                }
                s += __shfl_xor(s, 1); s += __shfl_xor(s, 2);
                s += __shfl_xor(s, 4); s += __shfl_xor(s, 8);
                if (lc == 0) atomicAdd(&rowsum[grow], s);
            }
        }
    } else {
        float colacc[4] = {0.0f, 0.0f, 0.0f, 0.0f};
        #pragma unroll
        for (int i = 0; i < 4; i++) {
            #pragma unroll
            for (int r = 0; r < 4; r++) {
                const int grow = rowBase + waveRow + 16 * i + quad * 4 + r;
                float s = 0.0f;
                #pragma unroll
                for (int j = 0; j < 4; j++) {
                    float e = __builtin_amdgcn_exp2f(acc[i][j][r] * EXP_SCALE);
                    s += e;
                    colacc[j] += e;
                }
                s += __shfl_xor(s, 1); s += __shfl_xor(s, 2);
                s += __shfl_xor(s, 4); s += __shfl_xor(s, 8);
                if (lc == 0) atomicAdd(&rowsum[grow], s);
            }
        }
        #pragma unroll
        for (int j = 0; j < 4; j++) {
            float c = colacc[j];
            c += __shfl_xor(c, 16); c += __shfl_xor(c, 32);
            if (lane < 16) atomicAdd(&rowsum[colBase + waveCol + 16 * j + lc], c);
        }
    }
}

// ---------------- K3: per-pair loss -> per-block partials (no atomics) ----
__global__ void __launch_bounds__(256) loss_kernel(
        const float* __restrict__ z1, const float* __restrict__ z2,
        const float* __restrict__ invnorm, const float* __restrict__ rowsum,
        float* __restrict__ partials) {
    const int tid  = threadIdx.x;
    const int wave = tid >> 6;
    const int lane = tid & 63;
    const int p = blockIdx.x * 4 + wave;     // 0..4095, one wave per pair
    float4 a = ((const float4*)(z1 + (size_t)p * DIM))[lane];
    float4 b = ((const float4*)(z2 + (size_t)p * DIM))[lane];
    float d = a.x * b.x + a.y * b.y + a.z * b.z + a.w * b.w;
    #pragma unroll
    for (int m = 1; m < 64; m <<= 1) d += __shfl_xor(d, m);
    __shared__ float wpart[4];
    if (lane == 0) {
        float sp = d * invnorm[p] * invnorm[p + NPAIR] * 10.0f;
        wpart[wave] = logf(rowsum[p]) + logf(rowsum[p + NPAIR]) - 2.0f * sp;
    }
    __syncthreads();
    if (tid == 0)
        partials[blockIdx.x] = wpart[0] + wpart[1] + wpart[2] + wpart[3];
}

// ---------------- K4: final reduce (single block) ----------------
__global__ void __launch_bounds__(256) final_kernel(
        const float* __restrict__ partials, float* __restrict__ out) {
    const int tid = threadIdx.x;
    float s = partials[tid] + partials[tid + 256]
            + partials[tid + 512] + partials[tid + 768];
    #pragma unroll
    for (int m = 1; m < 64; m <<= 1) s += __shfl_xor(s, m);
    __shared__ float wpart[4];
    if ((tid & 63) == 0) wpart[tid >> 6] = s;
    __syncthreads();
    if (tid == 0)
        out[0] = (wpart[0] + wpart[1] + wpart[2] + wpart[3]) * (1.0f / ROWS);
}

extern "C" void kernel_launch(void* const* d_in, const int* in_sizes, int n_in,
                              void* d_out, int out_size, void* d_ws, size_t ws_size,
                              hipStream_t stream) {
    const float* z1 = (const float*)d_in[0];
    const float* z2 = (const float*)d_in[1];
    float* out = (float*)d_out;

    char* ws = (char*)d_ws;
    unsigned short* zhat = (unsigned short*)ws;                         // 4 MiB
    float* invnorm  = (float*)(ws + (size_t)ROWS * DIM * 2);            // 32 KiB
    float* rowsum   = (float*)(ws + (size_t)ROWS * DIM * 2 + ROWS * 4); // 32 KiB
    float* partials = (float*)(ws + (size_t)ROWS * DIM * 2 + 2 * ROWS * 4); // 4 KiB

    prep_kernel<<<ROWS / 4, 256, 0, stream>>>(z1, z2, zhat, invnorm, rowsum);
    simsum_kernel<<<64 * 65 / 2, 256, 0, stream>>>(zhat, rowsum);
    loss_kernel<<<LOSS_BLOCKS, 256, 0, stream>>>(z1, z2, invnorm, rowsum, partials);
    final_kernel<<<1, 256, 0, stream>>>(partials, out);
}

// Round 4
// 116.404 us; speedup vs baseline: 2.0718x; 1.0547x over previous
//
#include <hip/hip_runtime.h>
#include <hip/hip_bf16.h>
#include <math.h>

// NT-Xent loss, N=4096, D=256 -> 2N=8192 rows.
// R4: fp8(e4m3, OCP) Gram kernel with FULL-K LDS staging -> ONE barrier/block.
//   R3 showed MfmaUtil 12%/VALU 18% with ~16K cyc per block (614 cyc of MFMA):
//   barrier-drain bound (8 syncs/block on a K=256 loop) + L2 thrash (bf16 zhat
//   = 4MB = exactly per-XCD L2). fp8 halves all bytes: zhat 2MB (L2-resident),
//   A+B full-K tiles = 64KB LDS -> single __syncthreads per block.
// K1 (prep): normalize + cvt_pk_fp8; zero rowsum.
// K2 (simsum): upper-tri 128x128 tiles (symmetric); mfma_f32_16x16x32_fp8_fp8;
//   glds width-16 staging, XOR swizzle (16B chunks, c_phys = c_log ^ (row&15),
//   applied on the GLOBAL fetch side -- glds dest is wave-uniform + lane*16).
// K3/K4: per-pair loss -> block partials -> single-block final reduce
//   (no contended single-address atomics; R2 lesson).

static constexpr int ROWS  = 8192;   // 2N
static constexpr int NPAIR = 4096;   // N
static constexpr int DIM   = 256;    // D (= 256 bytes per fp8 row)
static constexpr float EXP_SCALE = 14.426950408889634f;  // 10 / ln(2)
static constexpr int LOSS_BLOCKS = NPAIR / 4;            // 1024

typedef float f32x4 __attribute__((ext_vector_type(4)));

__device__ __forceinline__ void glds16(const void* g, void* l) {
    __builtin_amdgcn_global_load_lds(
        (const __attribute__((address_space(1))) void*)g,
        (__attribute__((address_space(3))) void*)l, 16, 0, 0);
}

// ---------------- K1: normalize -> fp8 + zero rowsum ----------------
__global__ void __launch_bounds__(256) prep_kernel(
        const float* __restrict__ z1, const float* __restrict__ z2,
        unsigned char* __restrict__ zhat, float* __restrict__ invnorm,
        float* __restrict__ rowsum) {
    const int tid  = threadIdx.x;
    const int wave = tid >> 6;
    const int lane = tid & 63;
    const int row  = blockIdx.x * 4 + wave;           // one wave per row
    const float* src = (row < NPAIR) ? (z1 + (size_t)row * DIM)
                                     : (z2 + (size_t)(row - NPAIR) * DIM);
    float4 v = ((const float4*)src)[lane];
    float ss = v.x * v.x + v.y * v.y + v.z * v.z + v.w * v.w;
    #pragma unroll
    for (int m = 1; m < 64; m <<= 1) ss += __shfl_xor(ss, m);
    float invn = 1.0f / fmaxf(sqrtf(ss), 1e-12f);
    int p = __builtin_amdgcn_cvt_pk_fp8_f32(v.x * invn, v.y * invn, 0, false);
    p     = __builtin_amdgcn_cvt_pk_fp8_f32(v.z * invn, v.w * invn, p, true);
    ((int*)(zhat + (size_t)row * DIM))[lane] = p;
    if (lane == 0) invnorm[row] = invn;
    if (tid < 4) rowsum[blockIdx.x * 4 + tid] = 0.0f;
}

// ---------------- K2: symmetric fused Gram (fp8), single barrier ----------
// grid: 64*65/2 = 2080 blocks, 256 threads, LDS 64KB -> 2 blocks/CU.
__global__ void __launch_bounds__(256, 2) simsum_kernel(
        const unsigned char* __restrict__ zs, float* __restrict__ rowsum) {
    __shared__ __align__(16) unsigned char As[128 * 256];
    __shared__ __align__(16) unsigned char Bs[128 * 256];

    // decode linear tile index -> (by, bx), bx >= by
    const int t = blockIdx.x;
    int by = (int)floorf((129.0f - sqrtf(16641.0f - 8.0f * (float)t)) * 0.5f);
    by = max(0, min(by, 63));
    while (64 * (by + 1) - ((by + 1) * by) / 2 <= t) by++;
    while (64 * by - (by * (by - 1)) / 2 > t) by--;
    const int bx = by + (t - (64 * by - (by * (by - 1)) / 2));
    const int rowBase = by * 128;
    const int colBase = bx * 128;
    const bool diag = (bx == by);

    const int tid  = threadIdx.x;
    const int wave = tid >> 6;
    const int lane = tid & 63;
    const int lc   = lane & 15;
    const int quad = lane >> 4;
    const int waveRow = (wave >> 1) * 64;
    const int waveCol = (wave & 1) * 64;

    // Staging: per glds instr a wave covers 4 rows x 256B. Lane L -> row
    // rA + (L>>4), physical 16B chunk L&15, which must hold LOGICAL chunk
    // (L&15) ^ (row & 15)  (XOR swizzle on the global fetch address).
    const int srow   = lane >> 4;   // 0..3
    const int c_phys = lane & 15;   // 16B chunk slot
    #pragma unroll
    for (int g = 0; g < 8; g++) {
        const int rA = wave * 32 + g * 4;
        const int r  = rA + srow;
        const int c_log = c_phys ^ (r & 15);
        glds16(zs + (size_t)(rowBase + r) * DIM + c_log * 16, &As[rA * 256]);
        glds16(zs + (size_t)(colBase + r) * DIM + c_log * 16, &Bs[rA * 256]);
    }
    __syncthreads();   // the ONLY barrier in this kernel

    f32x4 acc[4][4];
    #pragma unroll
    for (int i = 0; i < 4; i++)
        #pragma unroll
        for (int j = 0; j < 4; j++)
            acc[i][j] = (f32x4)(0.0f);

    // K loop: 8 steps of K=32; frag = 8 fp8 bytes, k = quad*8 + b.
    // Physical addr of logical 8B chunk k8 at row R: note R&15 == lc here.
    #pragma unroll
    for (int ks = 0; ks < DIM; ks += 32) {
        const int k8   = (ks >> 3) + quad;   // logical 8B chunk, 0..31
        const int coff = (((k8 >> 1) ^ lc) << 4) + ((k8 & 1) << 3);
        long af[4], bfr[4];
        #pragma unroll
        for (int i = 0; i < 4; i++) {
            const int R = waveRow + 16 * i + lc;
            af[i] = *(const long*)&As[R * 256 + coff];
        }
        #pragma unroll
        for (int j = 0; j < 4; j++) {
            const int R = waveCol + 16 * j + lc;
            bfr[j] = *(const long*)&Bs[R * 256 + coff];
        }
        #pragma unroll
        for (int i = 0; i < 4; i++)
            #pragma unroll
            for (int j = 0; j < 4; j++)
                acc[i][j] = __builtin_amdgcn_mfma_f32_16x16x32_fp8_fp8(
                    af[i], bfr[j], acc[i][j], 0, 0, 0);
    }

    // Epilogue. C/D 16x16 layout: col = lane&15, row = quad*4 + reg [m89,
    // dtype-independent per m121-m128].
    if (diag) {
        #pragma unroll
        for (int i = 0; i < 4; i++) {
            #pragma unroll
            for (int r = 0; r < 4; r++) {
                const int grow = rowBase + waveRow + 16 * i + quad * 4 + r;
                float s = 0.0f;
                #pragma unroll
                for (int j = 0; j < 4; j++) {
                    const int gcol = colBase + waveCol + 16 * j + lc;
                    float e = __builtin_amdgcn_exp2f(acc[i][j][r] * EXP_SCALE);
                    s += (grow == gcol) ? 0.0f : e;
                }
                s += __shfl_xor(s, 1); s += __shfl_xor(s, 2);
                s += __shfl_xor(s, 4); s += __shfl_xor(s, 8);
                if (lc == 0) atomicAdd(&rowsum[grow], s);
            }
        }
    } else {
        float colacc[4] = {0.0f, 0.0f, 0.0f, 0.0f};
        #pragma unroll
        for (int i = 0; i < 4; i++) {
            #pragma unroll
            for (int r = 0; r < 4; r++) {
                const int grow = rowBase + waveRow + 16 * i + quad * 4 + r;
                float s = 0.0f;
                #pragma unroll
                for (int j = 0; j < 4; j++) {
                    float e = __builtin_amdgcn_exp2f(acc[i][j][r] * EXP_SCALE);
                    s += e;
                    colacc[j] += e;
                }
                s += __shfl_xor(s, 1); s += __shfl_xor(s, 2);
                s += __shfl_xor(s, 4); s += __shfl_xor(s, 8);
                if (lc == 0) atomicAdd(&rowsum[grow], s);
            }
        }
        #pragma unroll
        for (int j = 0; j < 4; j++) {
            float c = colacc[j];
            c += __shfl_xor(c, 16); c += __shfl_xor(c, 32);
            if (lane < 16) atomicAdd(&rowsum[colBase + waveCol + 16 * j + lc], c);
        }
    }
}

// ---------------- K3: per-pair loss -> per-block partials ----------------
__global__ void __launch_bounds__(256) loss_kernel(
        const float* __restrict__ z1, const float* __restrict__ z2,
        const float* __restrict__ invnorm, const float* __restrict__ rowsum,
        float* __restrict__ partials) {
    const int tid  = threadIdx.x;
    const int wave = tid >> 6;
    const int lane = tid & 63;
    const int p = blockIdx.x * 4 + wave;     // one wave per pair
    float4 a = ((const float4*)(z1 + (size_t)p * DIM))[lane];
    float4 b = ((const float4*)(z2 + (size_t)p * DIM))[lane];
    float d = a.x * b.x + a.y * b.y + a.z * b.z + a.w * b.w;
    #pragma unroll
    for (int m = 1; m < 64; m <<= 1) d += __shfl_xor(d, m);
    __shared__ float wpart[4];
    if (lane == 0) {
        float sp = d * invnorm[p] * invnorm[p + NPAIR] * 10.0f;
        wpart[wave] = logf(rowsum[p]) + logf(rowsum[p + NPAIR]) - 2.0f * sp;
    }
    __syncthreads();
    if (tid == 0)
        partials[blockIdx.x] = wpart[0] + wpart[1] + wpart[2] + wpart[3];
}

// ---------------- K4: final reduce (single block) ----------------
__global__ void __launch_bounds__(256) final_kernel(
        const float* __restrict__ partials, float* __restrict__ out) {
    const int tid = threadIdx.x;
    float s = partials[tid] + partials[tid + 256]
            + partials[tid + 512] + partials[tid + 768];
    #pragma unroll
    for (int m = 1; m < 64; m <<= 1) s += __shfl_xor(s, m);
    __shared__ float wpart[4];
    if ((tid & 63) == 0) wpart[tid >> 6] = s;
    __syncthreads();
    if (tid == 0)
        out[0] = (wpart[0] + wpart[1] + wpart[2] + wpart[3]) * (1.0f / ROWS);
}

extern "C" void kernel_launch(void* const* d_in, const int* in_sizes, int n_in,
                              void* d_out, int out_size, void* d_ws, size_t ws_size,
                              hipStream_t stream) {
    const float* z1 = (const float*)d_in[0];
    const float* z2 = (const float*)d_in[1];
    float* out = (float*)d_out;

    char* ws = (char*)d_ws;
    unsigned char* zhat = (unsigned char*)ws;                      // 2 MiB
    float* invnorm  = (float*)(ws + (size_t)ROWS * DIM);           // 32 KiB
    float* rowsum   = (float*)(ws + (size_t)ROWS * DIM + ROWS * 4);      // 32 KiB
    float* partials = (float*)(ws + (size_t)ROWS * DIM + 2 * ROWS * 4);  // 4 KiB

    prep_kernel<<<ROWS / 4, 256, 0, stream>>>(z1, z2, zhat, invnorm, rowsum);
    simsum_kernel<<<64 * 65 / 2, 256, 0, stream>>>(zhat, rowsum);
    loss_kernel<<<LOSS_BLOCKS, 256, 0, stream>>>(z1, z2, invnorm, rowsum, partials);
    final_kernel<<<1, 256, 0, stream>>>(partials, out);
}

// Round 8
// 101.959 us; speedup vs baseline: 2.3654x; 1.1417x over previous
//
#include <hip/hip_runtime.h>
#include <hip/hip_bf16.h>
#include <math.h>

// NT-Xent loss, N=4096, D=256 -> 2N=8192 rows.
// R8: LDS-FREE Gram kernel ("flatmm" style). R4 evidence: LDS-staged tiles
// stall 67% of CU time (glds->vmcnt(0)->barrier->ds_read chains, 2 blocks/CU).
// Fix: store normalized fp8 in chunk-transposed zT[k8][row] (32 x 8192 x 8B)
// so every MFMA fragment is a direct coalesced global_load_dwordx2 (16 rows
// x 8B = 128B/quad-segment). No __shared__, no barriers in the K-loop;
// VGPR-bound occupancy; L2-resident (2MB x 8 XCD copies fits).
// K1 prep: normalize -> fp8, LDS-transpose -> zT; invnorm.
// K2 simsum: upper-tri 128x128 tiles, fp8 MFMA 16x16x32; privatized
//    no-atomic epilogue -> partial[128][8192] (unique writer/slot).
// K3 loss: folds rowsum reduction (128 partial slots/row) + positive-pair
//    dot -> blockpart[1024]. K4 final: 1 block -> out.

static constexpr int ROWS  = 8192;
static constexpr int NPAIR = 4096;
static constexpr int DIM   = 256;            // bytes per fp8 row
static constexpr int NTILE = 64 * 65 / 2;    // 2080
static constexpr float EXP_SCALE = 14.426950408889634f;  // 10/ln2
static constexpr size_t CH = 65536;          // bytes per zT chunk-row: 8192*8

typedef float f32x4 __attribute__((ext_vector_type(4)));

template <int CTRL>
__device__ __forceinline__ float dpp_add(float x) {
    int t = __builtin_amdgcn_update_dpp(
        0, __builtin_bit_cast(int, x), CTRL, 0xF, 0xF, true);
    return x + __builtin_bit_cast(float, t);
}
// butterfly sum over each 16-lane group (full-rate VALU DPP)
__device__ __forceinline__ float sum16(float x) {
    x = dpp_add<0xB1>(x);   // xor 1
    x = dpp_add<0x4E>(x);   // xor 2
    x = dpp_add<0x141>(x);  // xor 4 (row_half_mirror)
    x = dpp_add<0x140>(x);  // xor 8 (row_mirror)
    return x;
}
__device__ __forceinline__ float sum64(float x) {
    x = sum16(x);
    x += __shfl_xor(x, 16);
    x += __shfl_xor(x, 32);
    return x;
}

// ---------------- K1: normalize -> fp8 -> chunk-transposed zT ----------------
__global__ void __launch_bounds__(256) prep_kernel(
        const float* __restrict__ z1, const float* __restrict__ z2,
        unsigned char* __restrict__ zT, float* __restrict__ invnorm) {
    __shared__ int Ls[16 * 64];   // 16 rows x 256B
    const int tid  = threadIdx.x;
    const int wave = tid >> 6;
    const int lane = tid & 63;
    const int r0   = blockIdx.x * 16;

    #pragma unroll
    for (int it = 0; it < 4; ++it) {
        const int row = r0 + it * 4 + wave;
        const float* src = (row < NPAIR) ? (z1 + (size_t)row * DIM)
                                         : (z2 + (size_t)(row - NPAIR) * DIM);
        float4 v = ((const float4*)src)[lane];
        float ss = sum64(v.x * v.x + v.y * v.y + v.z * v.z + v.w * v.w);
        float invn = 1.0f / fmaxf(sqrtf(ss), 1e-12f);
        int p = __builtin_amdgcn_cvt_pk_fp8_f32(v.x * invn, v.y * invn, 0, false);
        p     = __builtin_amdgcn_cvt_pk_fp8_f32(v.z * invn, v.w * invn, p, true);
        Ls[(it * 4 + wave) * 64 + lane] = p;
        if (lane == 0) invnorm[row] = invn;
    }
    __syncthreads();
    // transpose out: thread t -> chunk k8 = t>>3, row pair rp = t&7
    const int k8 = tid >> 3;
    const int rp = (tid & 7) * 2;
    int4 o;
    o.x = Ls[rp * 64 + k8 * 2];
    o.y = Ls[rp * 64 + k8 * 2 + 1];
    o.z = Ls[(rp + 1) * 64 + k8 * 2];
    o.w = Ls[(rp + 1) * 64 + k8 * 2 + 1];
    *(int4*)(zT + (size_t)k8 * CH + (size_t)(r0 + rp) * 8) = o;
}

// ---------------- K2: symmetric fp8 Gram, LDS-free ----------------
__global__ void __launch_bounds__(256) simsum_kernel(
        const unsigned char* __restrict__ zT, float* __restrict__ partial) {
    // decode linear tile index -> (by, bx), bx >= by
    const int t = blockIdx.x;
    int by = (int)floorf((129.0f - sqrtf(16641.0f - 8.0f * (float)t)) * 0.5f);
    by = max(0, min(by, 63));
    while (64 * (by + 1) - ((by + 1) * by) / 2 <= t) by++;
    while (64 * by - (by * (by - 1)) / 2 > t) by--;
    const int bx = by + (t - (64 * by - (by * (by - 1)) / 2));
    const int rowBase = by * 128;
    const int colBase = bx * 128;

    const int tid  = threadIdx.x;
    const int wave = tid >> 6;
    const int lane = tid & 63;
    const int lc   = lane & 15;
    const int quad = lane >> 4;
    const int waveRow = (wave >> 1) * 64;
    const int waveCol = (wave & 1) * 64;

    const unsigned char* zA = zT + (size_t)quad * CH
                              + (size_t)(rowBase + waveRow + lc) * 8;
    const unsigned char* zB = zT + (size_t)quad * CH
                              + (size_t)(colBase + waveCol + lc) * 8;

    f32x4 acc[4][4];
    #pragma unroll
    for (int i = 0; i < 4; i++)
        #pragma unroll
        for (int j = 0; j < 4; j++)
            acc[i][j] = (f32x4)(0.0f);

    #pragma unroll
    for (int ks = 0; ks < 8; ks++) {
        long af[4], bfr[4];
        #pragma unroll
        for (int i = 0; i < 4; i++)
            af[i] = *(const long*)(zA + (size_t)ks * 4 * CH + i * 128);
        #pragma unroll
        for (int j = 0; j < 4; j++)
            bfr[j] = *(const long*)(zB + (size_t)ks * 4 * CH + j * 128);
        #pragma unroll
        for (int i = 0; i < 4; i++)
            #pragma unroll
            for (int j = 0; j < 4; j++)
                acc[i][j] = __builtin_amdgcn_mfma_f32_16x16x32_fp8_fp8(
                    af[i], bfr[j], acc[i][j], 0, 0, 0);
    }

    // Epilogue. C/D 16x16: col=lane&15, row=quad*4+reg [m89].
    // Privatized unique-writer slots: partial[slot][row].
    float* prow = partial + (size_t)(bx * 2 + (waveCol >> 6)) * ROWS;
    if (bx == by) {
        #pragma unroll
        for (int i = 0; i < 4; i++) {
            #pragma unroll
            for (int r = 0; r < 4; r++) {
                const int grow = rowBase + waveRow + 16 * i + quad * 4 + r;
                float s = 0.0f;
                #pragma unroll
                for (int j = 0; j < 4; j++) {
                    const int gcol = colBase + waveCol + 16 * j + lc;
                    float e = __builtin_amdgcn_exp2f(acc[i][j][r] * EXP_SCALE);
                    s += (grow == gcol) ? 0.0f : e;
                }
                s = sum16(s);
                if (lc == 0) prow[grow] = s;
            }
        }
    } else {
        float* pcol = partial + (size_t)(by * 2 + (waveRow >> 6)) * ROWS;
        float colacc[4] = {0.0f, 0.0f, 0.0f, 0.0f};
        #pragma unroll
        for (int i = 0; i < 4; i++) {
            #pragma unroll
            for (int r = 0; r < 4; r++) {
                const int grow = rowBase + waveRow + 16 * i + quad * 4 + r;
                float s = 0.0f;
                #pragma unroll
                for (int j = 0; j < 4; j++) {
                    float e = __builtin_amdgcn_exp2f(acc[i][j][r] * EXP_SCALE);
                    s += e;
                    colacc[j] += e;
                }
                s = sum16(s);
                if (lc == 0) prow[grow] = s;
            }
        }
        #pragma unroll
        for (int j = 0; j < 4; j++) {
            float c = colacc[j];
            c += __shfl_xor(c, 16);
            c += __shfl_xor(c, 32);
            if (lane < 16) pcol[colBase + waveCol + 16 * j + lc] = c;
        }
    }
}

// -------- K3: rowsum reduction + per-pair loss -> blockpart (no atomics) ----
__global__ void __launch_bounds__(256) loss_kernel(
        const float* __restrict__ z1, const float* __restrict__ z2,
        const float* __restrict__ invnorm, const float* __restrict__ partial,
        float* __restrict__ blockpart) {
    const int tid  = threadIdx.x;
    const int wave = tid >> 6;
    const int lane = tid & 63;
    const int p = blockIdx.x * 4 + wave;     // pair 0..4095; rows p, p+NPAIR
    // positive-pair dot (exact fp32)
    float4 a = ((const float4*)(z1 + (size_t)p * DIM))[lane];
    float4 b = ((const float4*)(z2 + (size_t)p * DIM))[lane];
    float d = sum64(a.x * b.x + a.y * b.y + a.z * b.z + a.w * b.w);
    // rowsums: 128 slots per row, 2 per lane
    float sp_ = partial[(size_t)lane * ROWS + p]
              + partial[(size_t)(lane + 64) * ROWS + p];
    float sq_ = partial[(size_t)lane * ROWS + p + NPAIR]
              + partial[(size_t)(lane + 64) * ROWS + p + NPAIR];
    sp_ = sum64(sp_);
    sq_ = sum64(sq_);
    __shared__ float wp[4];
    if (lane == 0) {
        float sim = d * invnorm[p] * invnorm[p + NPAIR] * 10.0f;
        wp[wave] = logf(sp_) + logf(sq_) - 2.0f * sim;
    }
    __syncthreads();
    if (tid == 0)
        blockpart[blockIdx.x] = wp[0] + wp[1] + wp[2] + wp[3];
}

// ---------------- K4: final reduce (single block) ----------------
__global__ void __launch_bounds__(256) final_kernel(
        const float* __restrict__ blockpart, float* __restrict__ out) {
    const int tid = threadIdx.x;
    float s = blockpart[tid] + blockpart[tid + 256]
            + blockpart[tid + 512] + blockpart[tid + 768];
    s = sum64(s);
    __shared__ float wpart[4];
    if ((tid & 63) == 0) wpart[tid >> 6] = s;
    __syncthreads();
    if (tid == 0)
        out[0] = (wpart[0] + wpart[1] + wpart[2] + wpart[3]) * (1.0f / ROWS);
}

extern "C" void kernel_launch(void* const* d_in, const int* in_sizes, int n_in,
                              void* d_out, int out_size, void* d_ws, size_t ws_size,
                              hipStream_t stream) {
    const float* z1 = (const float*)d_in[0];
    const float* z2 = (const float*)d_in[1];
    float* out = (float*)d_out;

    char* ws = (char*)d_ws;
    unsigned char* zT = (unsigned char*)ws;                         // 2 MiB
    float* partial   = (float*)(ws + (size_t)2 * 1024 * 1024);      // 4 MiB
    float* invnorm   = (float*)(ws + (size_t)6 * 1024 * 1024);      // 32 KiB
    float* blockpart = (float*)(ws + (size_t)6 * 1024 * 1024 + 32768); // 4 KiB

    prep_kernel<<<ROWS / 16, 256, 0, stream>>>(z1, z2, zT, invnorm);
    simsum_kernel<<<NTILE, 256, 0, stream>>>(zT, partial);
    loss_kernel<<<NPAIR / 4, 256, 0, stream>>>(z1, z2, invnorm, partial, blockpart);
    final_kernel<<<1, 256, 0, stream>>>(blockpart, out);
}